// Round 13
// baseline (227.294 us; speedup 1.0000x reference)
//
#include <hip/hip_runtime.h>

// NarrativeClassificationLoss — v16: global_load_lds double-buffered DMA.
// R15 post-mortem of v15 (66-68us @ 46% occ, clean counters): elimination
// matrix complete — occupancy, fetch volume, MLP batching, slices,
// atomics all non-levers. Little's law on the clean kernels shows only
// ~2KB outstanding per CU (~one row-load in flight); the pathological
// kernels (v6/v8) moved 2-3x the bytes FASTER because spill/atomic
// traffic accidentally raised request depth. hipcc will not hold >1
// register-target VMEM load open per wave (v14: batch compiled to the
// identical schedule). Fix = the untried ladder step: stage sub-row data
// with __builtin_amdgcn_global_load_lds (width 16) — DMA to LDS queues
// deep at zero VGPR cost. Double-buffered 4-row tiles (64KB LDS); each
// wave stages/consumes its own quarter-row => NO barriers in the loop:
// {issue 8 DMA for tile k+1 -> compute tile k from LDS (~2000cy, covers
// ~900cy latency) -> s_waitcnt vmcnt(0) drain}. Math/emit identical to
// v12/v14 (verified): fused single pass, zero atomics, exclusive tables.
//
// B=16384, N_NARR=128, N_SUB=1024, K=8, GAMMA=2, weights (1,1,0.5).

#define BDIM 256
#define NROWS 16384
#define NNARR 128
#define NSUB 1024
#define RPB 16
#define NBLOCKS (NROWS / RPB)              // 1024
#define TROWS 4                            // rows per LDS tile
#define NT (RPB / TROWS)                   // 4 tiles

// per-block table layout (floats)
#define WS_AN    0      // [128]  sum_b y*sp(-x)            (narrative)
#define WS_CN    128    // [128]  sum_b (1-y)*sp(x)
#define WS_NSUM  256    // [128]  col sums of narrative labels
#define WS_AS    384    // [1024] sum_b pos*y*sp(-x)        (subnarrative)
#define WS_CS    1408   // [1024] sum_b pos*(1-y)*sp(x)
#define WS_SSUM  2432   // [1024] col sums of sub labels
#define WS_FN    3456   // focal narrative sum
#define WS_FS    3457   // focal subnarrative sum
#define WS_HIER  3458   // hierarchy sum
#define WS_FLOATS 3459
#define CSTRIDE  3472   // table stride in floats (16B aligned)

#define NCHUNK 16                          // reduce fan-in groups
#define TPG (NBLOCKS / NCHUNK)             // 64 tables per group

typedef __attribute__((address_space(1))) const unsigned int as1_u32;
typedef __attribute__((address_space(3))) unsigned int as3_u32;

// 16B-per-lane async global->LDS copy. LDS dest must be wave-uniform;
// HW writes lds + lane*16. Global src is per-lane.
__device__ __forceinline__ void load16_lds(const void* g, void* l) {
    __builtin_amdgcn_global_load_lds((as1_u32*)g, (as3_u32*)l, 16, 0, 0);
}

__device__ __forceinline__ void bce_pieces(float x, float& sp_p, float& sp_m, float& sig) {
    float a = fabsf(x);
    float e = __expf(-a);              // exp(-|x|) in (0,1]
    float l = __logf(1.0f + e);        // ~log1p(e); err ~1e-7, fine after /2M
    sp_p = fmaxf(x, 0.0f) + l;
    sp_m = sp_p - x;
    float inv = __builtin_amdgcn_rcpf(1.0f + e);
    sig = (x >= 0.0f) ? inv : e * inv;
}

// one row of work, textually inline (v14-verified: no helper arrays ->
// no SROA failure / scratch). Accumulators captured from scope.
#define ROW_BODY(xs, ys, nx, posv)                                            \
  {                                                                           \
    float nsp_p, nsp_m, nsig;                                                 \
    bce_pieces((nx), nsp_p, nsp_m, nsig);                                     \
    const float xv0 = (xs).x, xv1 = (xs).y, xv2 = (xs).z, xv3 = (xs).w;       \
    const float yv0 = (float)(ys).x, yv1 = (float)(ys).y,                     \
                yv2 = (float)(ys).z, yv3 = (float)(ys).w;                     \
    float mymax = 0.0f;                                                       \
    {                                                                         \
      float sp_p, sp_m, sig;                                                  \
      bce_pieces(xv0, sp_p, sp_m, sig);                                       \
      As[0] += (posv) * yv0 * sp_m;                                           \
      Cs[0] += (posv) * (1.0f - yv0) * sp_p;                                  \
      ss[0] += yv0;                                                           \
      float om = 1.0f - sig;                                                  \
      fs += om * om * yv0 * (-sp_m);                                          \
      mymax = fmaxf(mymax, sig);                                              \
    }                                                                         \
    {                                                                         \
      float sp_p, sp_m, sig;                                                  \
      bce_pieces(xv1, sp_p, sp_m, sig);                                       \
      As[1] += (posv) * yv1 * sp_m;                                           \
      Cs[1] += (posv) * (1.0f - yv1) * sp_p;                                  \
      ss[1] += yv1;                                                           \
      float om = 1.0f - sig;                                                  \
      fs += om * om * yv1 * (-sp_m);                                          \
      mymax = fmaxf(mymax, sig);                                              \
    }                                                                         \
    {                                                                         \
      float sp_p, sp_m, sig;                                                  \
      bce_pieces(xv2, sp_p, sp_m, sig);                                       \
      As[2] += (posv) * yv2 * sp_m;                                           \
      Cs[2] += (posv) * (1.0f - yv2) * sp_p;                                  \
      ss[2] += yv2;                                                           \
      float om = 1.0f - sig;                                                  \
      fs += om * om * yv2 * (-sp_m);                                          \
      mymax = fmaxf(mymax, sig);                                              \
    }                                                                         \
    {                                                                         \
      float sp_p, sp_m, sig;                                                  \
      bce_pieces(xv3, sp_p, sp_m, sig);                                       \
      As[3] += (posv) * yv3 * sp_m;                                           \
      Cs[3] += (posv) * (1.0f - yv3) * sp_p;                                  \
      ss[3] += yv3;                                                           \
      float om = 1.0f - sig;                                                  \
      fs += om * om * yv3 * (-sp_m);                                          \
      mymax = fmaxf(mymax, sig);                                              \
    }                                                                         \
    float gmax = fmaxf(mymax, __shfl_xor(mymax, 1, 64));                      \
    if ((t & 1) == 0) {                                                       \
        hier += fmaxf(gmax - nsig, 0.0f) * (posv);                            \
        An += (posv) * nsp_m;                                                 \
        Cn += (1.0f - (posv)) * nsp_p;                                        \
        ns += (posv);                                                         \
        float om = 1.0f - nsig;                                               \
        fn += om * om * (posv) * (-nsp_m);                                    \
    }                                                                         \
  }

// stage TROWS rows of slog+slab into buffer `buf`. Each wave w covers
// bytes [w*1024,(w+1)*1024) of each 4KB row (its own lanes' quads), so
// staging and consumption are wave-local: no barrier needed.
#define STAGE(buf, tile)                                                      \
  {                                                                           \
    const int rbase = r0 + (tile) * TROWS;                                    \
    _Pragma("unroll")                                                         \
    for (int rr = 0; rr < TROWS; ++rr) {                                      \
      const size_t roff = (size_t)(rbase + rr) * NSUB + 4 * (size_t)t;        \
      load16_lds(slog + roff, &ls_x[buf][rr][(t >> 6) << 8]);                 \
      load16_lds(slab + roff, &ls_y[buf][rr][(t >> 6) << 8]);                 \
    }                                                                         \
  }

#define COMPUTE(buf, tile)                                                    \
  {                                                                           \
    _Pragma("unroll")                                                         \
    for (int rr = 0; rr < TROWS; ++rr) {                                      \
      const int r = r0 + (tile) * TROWS + rr;                                 \
      const float4 xs = *(const float4*)&ls_x[buf][rr][4 * t];                \
      const int4   ys = *(const int4*)  &ls_y[buf][rr][4 * t];                \
      const float  nx   = nlog[(size_t)r * NNARR + g];                        \
      const float  posv = (float)nlab[(size_t)r * NNARR + g];                 \
      ROW_BODY(xs, ys, nx, posv);                                             \
    }                                                                         \
  }

__global__ __launch_bounds__(BDIM) void ncl_main(
    const float* __restrict__ nlog, const float* __restrict__ slog,
    const int*   __restrict__ nlab, const int*   __restrict__ slab,
    float* __restrict__ P)
{
    __shared__ float ls_x[2][TROWS][NSUB];   // 32 KB
    __shared__ int   ls_y[2][TROWS][NSUB];   // 32 KB
    __shared__ float ssc[4][3];              // per-wave scalar partials

    const int t  = threadIdx.x;
    const int g  = t >> 1;
    const int r0 = blockIdx.x * RPB;
    float* const Pb = P + (size_t)blockIdx.x * CSTRIDE;

    float As[4] = {0,0,0,0}, Cs[4] = {0,0,0,0}, ss[4] = {0,0,0,0};
    float An = 0.f, Cn = 0.f, ns = 0.f, fn = 0.f, fs = 0.f, hier = 0.f;

    STAGE(0, 0);
    asm volatile("s_waitcnt vmcnt(0)" ::: "memory");

    #pragma unroll
    for (int tile = 0; tile < NT; ++tile) {
        const int cb = tile & 1;
        if (tile + 1 < NT) STAGE(cb ^ 1, tile + 1);   // issue next tile's DMA
        COMPUTE(cb, tile);                            // ~2000cy, hides latency
        if (tile + 1 < NT)
            asm volatile("s_waitcnt vmcnt(0)" ::: "memory");  // cheap drain
    }

    // exclusive per-block table: plain stores, no atomics.
    *(float4*)(Pb + WS_AS   + 4 * t) = make_float4(As[0], As[1], As[2], As[3]);
    *(float4*)(Pb + WS_CS   + 4 * t) = make_float4(Cs[0], Cs[1], Cs[2], Cs[3]);
    *(float4*)(Pb + WS_SSUM + 4 * t) = make_float4(ss[0], ss[1], ss[2], ss[3]);
    if ((t & 1) == 0) {
        Pb[WS_AN   + g] = An;
        Pb[WS_CN   + g] = Cn;
        Pb[WS_NSUM + g] = ns;
    }

    // scalar partials: wave shuffle reduce -> LDS -> thread 0
    #pragma unroll
    for (int off = 32; off; off >>= 1) {
        fn   += __shfl_down(fn,   off, 64);
        fs   += __shfl_down(fs,   off, 64);
        hier += __shfl_down(hier, off, 64);
    }
    if ((t & 63) == 0) {
        int w = t >> 6;
        ssc[w][0] = fn; ssc[w][1] = fs; ssc[w][2] = hier;
    }
    __syncthreads();
    if (t == 0) {
        float a = 0.f, b = 0.f, c = 0.f;
        #pragma unroll
        for (int w = 0; w < 4; ++w) { a += ssc[w][0]; b += ssc[w][1]; c += ssc[w][2]; }
        Pb[WS_FN] = a; Pb[WS_FS] = b; Pb[WS_HIER] = c;
    }
}

// reduce: block (e-chunk, g) sums TPG tables -> tmp[g]; fully coalesced.
__global__ __launch_bounds__(256) void ncl_reduce1(const float* __restrict__ P,
                                                   float* __restrict__ tmp)
{
    const int e = blockIdx.x * 256 + threadIdx.x;
    if (e >= WS_FLOATS) return;
    const int gg = blockIdx.y;
    const float* p = P + (size_t)gg * TPG * CSTRIDE + e;
    float s = 0.f;
    #pragma unroll 4
    for (int i = 0; i < TPG; ++i)
        s += p[(size_t)i * CSTRIDE];
    tmp[(size_t)gg * CSTRIDE + e] = s;
}

__global__ __launch_bounds__(1024) void ncl_finalize(const float* __restrict__ tmp,
                                                     float* __restrict__ out)
{
    __shared__ float sr[6][16];
    const int t = threadIdx.x;
    const float Bf = (float)NROWS;

    // sub column t, summed over the 16 chunk tables (coalesced across t)
    float As = 0.f, Csv = 0.f, ss = 0.f;
    #pragma unroll 4
    for (int gc = 0; gc < NCHUNK; ++gc) {
        const float* p = tmp + (size_t)gc * CSTRIDE;
        As  += p[WS_AS   + t];
        Csv += p[WS_CS   + t];
        ss  += p[WS_SSUM + t];
    }
    float spw = fminf(fmaxf((Bf - ss) / (ss + 1e-6f), 1.0f), 50.0f);
    float sub_part = spw * As + Csv;

    float narr_part = 0.f, valid_part = 0.f;
    if (t < NNARR) {
        float An = 0.f, Cn = 0.f, ns = 0.f;
        #pragma unroll 4
        for (int gc = 0; gc < NCHUNK; ++gc) {
            const float* p = tmp + (size_t)gc * CSTRIDE;
            An += p[WS_AN + t]; Cn += p[WS_CN + t]; ns += p[WS_NSUM + t];
        }
        float npw = fminf(fmaxf((Bf - ns) / (ns + 1e-6f), 1.0f), 50.0f);
        narr_part  = npw * An + Cn;
        valid_part = ns;
    }

    float fn_p = 0.f, fs_p = 0.f, hier_p = 0.f;
    if (t < NCHUNK) {
        const float* p = tmp + (size_t)t * CSTRIDE;
        fn_p = p[WS_FN]; fs_p = p[WS_FS]; hier_p = p[WS_HIER];
    }

    #pragma unroll
    for (int off = 32; off; off >>= 1) {
        sub_part   += __shfl_down(sub_part,   off, 64);
        narr_part  += __shfl_down(narr_part,  off, 64);
        valid_part += __shfl_down(valid_part, off, 64);
        fn_p       += __shfl_down(fn_p,       off, 64);
        fs_p       += __shfl_down(fs_p,       off, 64);
        hier_p     += __shfl_down(hier_p,     off, 64);
    }
    if ((t & 63) == 0) {
        int w = t >> 6;
        sr[0][w] = sub_part; sr[1][w] = narr_part; sr[2][w] = valid_part;
        sr[3][w] = fn_p;     sr[4][w] = fs_p;      sr[5][w] = hier_p;
    }
    __syncthreads();
    if (t == 0) {
        float sub_tot = 0.f, narr_tot = 0.f, valid = 0.f;
        float fn = 0.f, fs = 0.f, hier = 0.f;
        #pragma unroll
        for (int i = 0; i < 16; ++i) {
            sub_tot += sr[0][i]; narr_tot += sr[1][i]; valid += sr[2][i];
            fn += sr[3][i]; fs += sr[4][i]; hier += sr[5][i];
        }

        float narrative_loss = narr_tot / (Bf * (float)NNARR);
        float sub_loss = (valid > 0.0f) ? (sub_tot * (1.0f / 8.0f)) / fmaxf(valid, 1.0f) : 0.0f;
        float nf = fn / (Bf * (float)NNARR);
        float sf = fs / (Bf * (float)NSUB);
        float hier_loss = hier / Bf;

        out[0] = (narrative_loss - 0.1f * nf)
               + (sub_loss       - 0.1f * sf)
               + 0.5f * hier_loss;
    }
}

extern "C" void kernel_launch(void* const* d_in, const int* in_sizes, int n_in,
                              void* d_out, int out_size, void* d_ws, size_t ws_size,
                              hipStream_t stream) {
    const float* nlog = (const float*)d_in[0];
    const float* slog = (const float*)d_in[1];
    const int*   nlab = (const int*)d_in[2];
    const int*   slab = (const int*)d_in[3];
    float* P   = (float*)d_ws;                        // 1024 tables
    float* tmp = P + (size_t)NBLOCKS * CSTRIDE;       // 16 group tables
    float* out = (float*)d_out;

    // all workspace cells are exclusively written before read: no memset.
    ncl_main<<<NBLOCKS, BDIM, 0, stream>>>(nlog, slog, nlab, slab, P);
    dim3 gr((WS_FLOATS + 255) / 256, NCHUNK);
    ncl_reduce1<<<gr, 256, 0, stream>>>(P, tmp);
    ncl_finalize<<<1, 1024, 0, stream>>>(tmp, out);
}

// Round 15
// 184.075 us; speedup vs baseline: 1.2348x; 1.2348x over previous
//
#include <hip/hip_runtime.h>

// NarrativeClassificationLoss — v17b: sched_barrier-fenced 4-row batches.
// (identical to v17; R14 bench failure was infra — container died twice,
//  kernel never ran. Resubmitting for measurement. Same happened at R11
//  -> clean run on resubmit.)
// Theory (R13): hipcc re-serializes loads to minimize VGPR — v12/v14/v15
// all compile to the same ~50-VGPR, ~1-row-in-flight schedule. Dirty
// kernels (v6/v8) moved 2-3x bytes at higher BW because spill traffic
// accidentally raised request depth. Fix: __builtin_amdgcn_sched_barrier(0)
// is binding — loads above can't sink, compute below can't hoist ->
// ~8 VMEM/wave in flight per 4-row batch (~30x today's depth). ~80 VGPR
// needed, 128 budget under waves_per_eu(4,4) (v12-verified spill-free).
// Macro row-body (v14-verified: no helper arrays -> no scratch).
// Zero atomics, exclusive tables, 3 dispatches, no memset.
// Falsifier: VGPR stays ~52 => fence defeated; WRITE >> 20MB => spill;
// main ~63us clean => service-rate roofline, declare it.
//
// B=16384, N_NARR=128, N_SUB=1024, K=8, GAMMA=2, weights (1,1,0.5).

#define BDIM 256
#define NROWS 16384
#define NNARR 128
#define NSUB 1024
#define RPB 16
#define NBLOCKS (NROWS / RPB)              // 1024

// per-block table layout (floats)
#define WS_AN    0      // [128]  sum_b y*sp(-x)            (narrative)
#define WS_CN    128    // [128]  sum_b (1-y)*sp(x)
#define WS_NSUM  256    // [128]  col sums of narrative labels
#define WS_AS    384    // [1024] sum_b pos*y*sp(-x)        (subnarrative)
#define WS_CS    1408   // [1024] sum_b pos*(1-y)*sp(x)
#define WS_SSUM  2432   // [1024] col sums of sub labels
#define WS_FN    3456   // focal narrative sum
#define WS_FS    3457   // focal subnarrative sum
#define WS_HIER  3458   // hierarchy sum
#define WS_FLOATS 3459
#define CSTRIDE  3472   // table stride in floats (16B aligned)

#define NCHUNK 16                          // reduce fan-in groups
#define TPG (NBLOCKS / NCHUNK)             // 64 tables per group

__device__ __forceinline__ void bce_pieces(float x, float& sp_p, float& sp_m, float& sig) {
    float a = fabsf(x);
    float e = __expf(-a);              // exp(-|x|) in (0,1]
    float l = __logf(1.0f + e);        // ~log1p(e); err ~1e-7, fine after /2M
    sp_p = fmaxf(x, 0.0f) + l;
    sp_m = sp_p - x;
    float inv = __builtin_amdgcn_rcpf(1.0f + e);
    sig = (x >= 0.0f) ? inv : e * inv;
}

// one row of work, textually inline (v14-verified: no helper arrays ->
// no SROA failure / scratch). Accumulators captured from scope.
#define ROW_BODY(xs, ys, nx, posv)                                            \
  {                                                                           \
    float nsp_p, nsp_m, nsig;                                                 \
    bce_pieces((nx), nsp_p, nsp_m, nsig);                                     \
    const float xv0 = (xs).x, xv1 = (xs).y, xv2 = (xs).z, xv3 = (xs).w;       \
    const float yv0 = (float)(ys).x, yv1 = (float)(ys).y,                     \
                yv2 = (float)(ys).z, yv3 = (float)(ys).w;                     \
    float mymax = 0.0f;                                                       \
    {                                                                         \
      float sp_p, sp_m, sig;                                                  \
      bce_pieces(xv0, sp_p, sp_m, sig);                                       \
      As[0] += (posv) * yv0 * sp_m;                                           \
      Cs[0] += (posv) * (1.0f - yv0) * sp_p;                                  \
      ss[0] += yv0;                                                           \
      float om = 1.0f - sig;                                                  \
      fs += om * om * yv0 * (-sp_m);                                          \
      mymax = fmaxf(mymax, sig);                                              \
    }                                                                         \
    {                                                                         \
      float sp_p, sp_m, sig;                                                  \
      bce_pieces(xv1, sp_p, sp_m, sig);                                       \
      As[1] += (posv) * yv1 * sp_m;                                           \
      Cs[1] += (posv) * (1.0f - yv1) * sp_p;                                  \
      ss[1] += yv1;                                                           \
      float om = 1.0f - sig;                                                  \
      fs += om * om * yv1 * (-sp_m);                                          \
      mymax = fmaxf(mymax, sig);                                              \
    }                                                                         \
    {                                                                         \
      float sp_p, sp_m, sig;                                                  \
      bce_pieces(xv2, sp_p, sp_m, sig);                                       \
      As[2] += (posv) * yv2 * sp_m;                                           \
      Cs[2] += (posv) * (1.0f - yv2) * sp_p;                                  \
      ss[2] += yv2;                                                           \
      float om = 1.0f - sig;                                                  \
      fs += om * om * yv2 * (-sp_m);                                          \
      mymax = fmaxf(mymax, sig);                                              \
    }                                                                         \
    {                                                                         \
      float sp_p, sp_m, sig;                                                  \
      bce_pieces(xv3, sp_p, sp_m, sig);                                       \
      As[3] += (posv) * yv3 * sp_m;                                           \
      Cs[3] += (posv) * (1.0f - yv3) * sp_p;                                  \
      ss[3] += yv3;                                                           \
      float om = 1.0f - sig;                                                  \
      fs += om * om * yv3 * (-sp_m);                                          \
      mymax = fmaxf(mymax, sig);                                              \
    }                                                                         \
    float gmax = fmaxf(mymax, __shfl_xor(mymax, 1, 64));                      \
    if ((t & 1) == 0) {                                                       \
        hier += fmaxf(gmax - nsig, 0.0f) * (posv);                            \
        An += (posv) * nsp_m;                                                 \
        Cn += (1.0f - (posv)) * nsp_p;                                        \
        ns += (posv);                                                         \
        float om = 1.0f - nsig;                                               \
        fn += om * om * (posv) * (-nsp_m);                                    \
    }                                                                         \
  }

__global__ void __launch_bounds__(BDIM)
__attribute__((amdgpu_waves_per_eu(4, 4)))
ncl_main(
    const float* __restrict__ nlog, const float* __restrict__ slog,
    const int*   __restrict__ nlab, const int*   __restrict__ slab,
    float* __restrict__ P)
{
    __shared__ float ssc[4][3];        // per-wave scalar partials

    const int t  = threadIdx.x;
    const int g  = t >> 1;
    const int r0 = blockIdx.x * RPB;
    float* const Pb = P + (size_t)blockIdx.x * CSTRIDE;

    float As[4] = {0,0,0,0}, Cs[4] = {0,0,0,0}, ss[4] = {0,0,0,0};
    float An = 0.f, Cn = 0.f, ns = 0.f, fn = 0.f, fs = 0.f, hier = 0.f;

    const float* sp = slog + (size_t)r0 * NSUB + 4 * t;
    const int*   lp = slab + (size_t)r0 * NSUB + 4 * t;
    const float* np = nlog + (size_t)r0 * NNARR + g;
    const int*   mp = nlab + (size_t)r0 * NNARR + g;

    // 4 batches of 4 rows. All 12 loads of a batch are issued before the
    // sched_barrier(0); no compute may hoist above it, no load may sink
    // below it -> ~8 VMEM in flight per wave during each compute block.
    #pragma unroll 1
    for (int i = 0; i < RPB; i += 4) {
        const float4 xs0 = *(const float4*)(sp + (size_t)(i + 0) * NSUB);
        const float4 xs1 = *(const float4*)(sp + (size_t)(i + 1) * NSUB);
        const float4 xs2 = *(const float4*)(sp + (size_t)(i + 2) * NSUB);
        const float4 xs3 = *(const float4*)(sp + (size_t)(i + 3) * NSUB);
        const int4   ys0 = *(const int4*)  (lp + (size_t)(i + 0) * NSUB);
        const int4   ys1 = *(const int4*)  (lp + (size_t)(i + 1) * NSUB);
        const int4   ys2 = *(const int4*)  (lp + (size_t)(i + 2) * NSUB);
        const int4   ys3 = *(const int4*)  (lp + (size_t)(i + 3) * NSUB);
        const float  nx0 = np[(size_t)(i + 0) * NNARR];
        const float  nx1 = np[(size_t)(i + 1) * NNARR];
        const float  nx2 = np[(size_t)(i + 2) * NNARR];
        const float  nx3 = np[(size_t)(i + 3) * NNARR];
        const float  pv0 = (float)mp[(size_t)(i + 0) * NNARR];
        const float  pv1 = (float)mp[(size_t)(i + 1) * NNARR];
        const float  pv2 = (float)mp[(size_t)(i + 2) * NNARR];
        const float  pv3 = (float)mp[(size_t)(i + 3) * NNARR];

        __builtin_amdgcn_sched_barrier(0);   // loads stay above, compute below

        ROW_BODY(xs0, ys0, nx0, pv0);
        ROW_BODY(xs1, ys1, nx1, pv1);
        ROW_BODY(xs2, ys2, nx2, pv2);
        ROW_BODY(xs3, ys3, nx3, pv3);
    }

    // exclusive per-block table: plain stores, no atomics.
    *(float4*)(Pb + WS_AS   + 4 * t) = make_float4(As[0], As[1], As[2], As[3]);
    *(float4*)(Pb + WS_CS   + 4 * t) = make_float4(Cs[0], Cs[1], Cs[2], Cs[3]);
    *(float4*)(Pb + WS_SSUM + 4 * t) = make_float4(ss[0], ss[1], ss[2], ss[3]);
    if ((t & 1) == 0) {
        Pb[WS_AN   + g] = An;
        Pb[WS_CN   + g] = Cn;
        Pb[WS_NSUM + g] = ns;
    }

    // scalar partials: wave shuffle reduce -> LDS -> thread 0
    #pragma unroll
    for (int off = 32; off; off >>= 1) {
        fn   += __shfl_down(fn,   off, 64);
        fs   += __shfl_down(fs,   off, 64);
        hier += __shfl_down(hier, off, 64);
    }
    if ((t & 63) == 0) {
        int w = t >> 6;
        ssc[w][0] = fn; ssc[w][1] = fs; ssc[w][2] = hier;
    }
    __syncthreads();
    if (t == 0) {
        float a = 0.f, b = 0.f, c = 0.f;
        #pragma unroll
        for (int w = 0; w < 4; ++w) { a += ssc[w][0]; b += ssc[w][1]; c += ssc[w][2]; }
        Pb[WS_FN] = a; Pb[WS_FS] = b; Pb[WS_HIER] = c;
    }
}

// reduce: block (e-chunk, g) sums TPG tables -> tmp[g]; fully coalesced.
__global__ __launch_bounds__(256) void ncl_reduce1(const float* __restrict__ P,
                                                   float* __restrict__ tmp)
{
    const int e = blockIdx.x * 256 + threadIdx.x;
    if (e >= WS_FLOATS) return;
    const int gg = blockIdx.y;
    const float* p = P + (size_t)gg * TPG * CSTRIDE + e;
    float s = 0.f;
    #pragma unroll 4
    for (int i = 0; i < TPG; ++i)
        s += p[(size_t)i * CSTRIDE];
    tmp[(size_t)gg * CSTRIDE + e] = s;
}

__global__ __launch_bounds__(1024) void ncl_finalize(const float* __restrict__ tmp,
                                                     float* __restrict__ out)
{
    __shared__ float sr[6][16];
    const int t = threadIdx.x;
    const float Bf = (float)NROWS;

    // sub column t, summed over the 16 chunk tables (coalesced across t)
    float As = 0.f, Csv = 0.f, ss = 0.f;
    #pragma unroll 4
    for (int gc = 0; gc < NCHUNK; ++gc) {
        const float* p = tmp + (size_t)gc * CSTRIDE;
        As  += p[WS_AS   + t];
        Csv += p[WS_CS   + t];
        ss  += p[WS_SSUM + t];
    }
    float spw = fminf(fmaxf((Bf - ss) / (ss + 1e-6f), 1.0f), 50.0f);
    float sub_part = spw * As + Csv;

    float narr_part = 0.f, valid_part = 0.f;
    if (t < NNARR) {
        float An = 0.f, Cn = 0.f, ns = 0.f;
        #pragma unroll 4
        for (int gc = 0; gc < NCHUNK; ++gc) {
            const float* p = tmp + (size_t)gc * CSTRIDE;
            An += p[WS_AN + t]; Cn += p[WS_CN + t]; ns += p[WS_NSUM + t];
        }
        float npw = fminf(fmaxf((Bf - ns) / (ns + 1e-6f), 1.0f), 50.0f);
        narr_part  = npw * An + Cn;
        valid_part = ns;
    }

    float fn_p = 0.f, fs_p = 0.f, hier_p = 0.f;
    if (t < NCHUNK) {
        const float* p = tmp + (size_t)t * CSTRIDE;
        fn_p = p[WS_FN]; fs_p = p[WS_FS]; hier_p = p[WS_HIER];
    }

    #pragma unroll
    for (int off = 32; off; off >>= 1) {
        sub_part   += __shfl_down(sub_part,   off, 64);
        narr_part  += __shfl_down(narr_part,  off, 64);
        valid_part += __shfl_down(valid_part, off, 64);
        fn_p       += __shfl_down(fn_p,       off, 64);
        fs_p       += __shfl_down(fs_p,       off, 64);
        hier_p     += __shfl_down(hier_p,     off, 64);
    }
    if ((t & 63) == 0) {
        int w = t >> 6;
        sr[0][w] = sub_part; sr[1][w] = narr_part; sr[2][w] = valid_part;
        sr[3][w] = fn_p;     sr[4][w] = fs_p;      sr[5][w] = hier_p;
    }
    __syncthreads();
    if (t == 0) {
        float sub_tot = 0.f, narr_tot = 0.f, valid = 0.f;
        float fn = 0.f, fs = 0.f, hier = 0.f;
        #pragma unroll
        for (int i = 0; i < 16; ++i) {
            sub_tot += sr[0][i]; narr_tot += sr[1][i]; valid += sr[2][i];
            fn += sr[3][i]; fs += sr[4][i]; hier += sr[5][i];
        }

        float narrative_loss = narr_tot / (Bf * (float)NNARR);
        float sub_loss = (valid > 0.0f) ? (sub_tot * (1.0f / 8.0f)) / fmaxf(valid, 1.0f) : 0.0f;
        float nf = fn / (Bf * (float)NNARR);
        float sf = fs / (Bf * (float)NSUB);
        float hier_loss = hier / Bf;

        out[0] = (narrative_loss - 0.1f * nf)
               + (sub_loss       - 0.1f * sf)
               + 0.5f * hier_loss;
    }
}

extern "C" void kernel_launch(void* const* d_in, const int* in_sizes, int n_in,
                              void* d_out, int out_size, void* d_ws, size_t ws_size,
                              hipStream_t stream) {
    const float* nlog = (const float*)d_in[0];
    const float* slog = (const float*)d_in[1];
    const int*   nlab = (const int*)d_in[2];
    const int*   slab = (const int*)d_in[3];
    float* P   = (float*)d_ws;                        // 1024 tables
    float* tmp = P + (size_t)NBLOCKS * CSTRIDE;       // 16 group tables
    float* out = (float*)d_out;

    // all workspace cells are exclusively written before read: no memset.
    ncl_main<<<NBLOCKS, BDIM, 0, stream>>>(nlog, slog, nlab, slab, P);
    dim3 gr((WS_FLOATS + 255) / 256, NCHUNK);
    ncl_reduce1<<<gr, 256, 0, stream>>>(P, tmp);
    ncl_finalize<<<1, 1024, 0, stream>>>(tmp, out);
}

// Round 16
// 180.336 us; speedup vs baseline: 1.2604x; 1.0207x over previous
//
#include <hip/hip_runtime.h>

// NarrativeClassificationLoss — v18: inline-asm forced 4-row load batch.
// R15 post-mortem of v17 (65us, VGPR 52 clean): sched_barrier(0) was
// DEFEATED — it binds the scheduler, but the register ALLOCATOR still
// splits the batch back into load->wait->use chains (needs fewer regs).
// v12/v14/v15/v17 all compile to the same ~52-VGPR serial-load schedule.
// The one mechanism the compiler cannot undo: asm volatile loads.
// They are ordered among themselves and their outputs MUST be allocated
// -> 8 global_load_dwordx4 issued back-to-back = 8-deep VMEM pipeline
// per wave per batch (vs ~1 today). Drain = asm s_waitcnt vmcnt(0) +
// sched_barrier(0) (rule: compiler hoists register-only ops past asm
// waitcnt otherwise). ~75 VGPR needed, 128 budget (waves_per_eu(4,4),
// v12-verified spill-free at this structure).
// Zero atomics, exclusive tables, 3 dispatches, no memset.
// Pre-committed: main drops -> depth was the constraint; main ~63-66us
// at VGPR>=85 clean -> elimination matrix complete, declare roofline.
//
// B=16384, N_NARR=128, N_SUB=1024, K=8, GAMMA=2, weights (1,1,0.5).

#define BDIM 256
#define NROWS 16384
#define NNARR 128
#define NSUB 1024
#define RPB 16
#define NBLOCKS (NROWS / RPB)              // 1024

// per-block table layout (floats)
#define WS_AN    0      // [128]  sum_b y*sp(-x)            (narrative)
#define WS_CN    128    // [128]  sum_b (1-y)*sp(x)
#define WS_NSUM  256    // [128]  col sums of narrative labels
#define WS_AS    384    // [1024] sum_b pos*y*sp(-x)        (subnarrative)
#define WS_CS    1408   // [1024] sum_b pos*(1-y)*sp(x)
#define WS_SSUM  2432   // [1024] col sums of sub labels
#define WS_FN    3456   // focal narrative sum
#define WS_FS    3457   // focal subnarrative sum
#define WS_HIER  3458   // hierarchy sum
#define WS_FLOATS 3459
#define CSTRIDE  3472   // table stride in floats (16B aligned)

#define NCHUNK 16                          // reduce fan-in groups
#define TPG (NBLOCKS / NCHUNK)             // 64 tables per group

// compiler cannot serialize these: volatile, ordered, outputs allocated.
#define ASM_LOADX4F(dst, ptr) \
  asm volatile("global_load_dwordx4 %0, %1, off" : "=v"(dst) : "v"(ptr))
#define ASM_LOADX4I(dst, ptr) \
  asm volatile("global_load_dwordx4 %0, %1, off" : "=v"(dst) : "v"(ptr))

__device__ __forceinline__ void bce_pieces(float x, float& sp_p, float& sp_m, float& sig) {
    float a = fabsf(x);
    float e = __expf(-a);              // exp(-|x|) in (0,1]
    float l = __logf(1.0f + e);        // ~log1p(e); err ~1e-7, fine after /2M
    sp_p = fmaxf(x, 0.0f) + l;
    sp_m = sp_p - x;
    float inv = __builtin_amdgcn_rcpf(1.0f + e);
    sig = (x >= 0.0f) ? inv : e * inv;
}

// one row of work, textually inline (v14-verified: no helper arrays ->
// no SROA failure / scratch). Accumulators captured from scope.
#define ROW_BODY(xs, ys, nx, posv)                                            \
  {                                                                           \
    float nsp_p, nsp_m, nsig;                                                 \
    bce_pieces((nx), nsp_p, nsp_m, nsig);                                     \
    const float xv0 = (xs).x, xv1 = (xs).y, xv2 = (xs).z, xv3 = (xs).w;       \
    const float yv0 = (float)(ys).x, yv1 = (float)(ys).y,                     \
                yv2 = (float)(ys).z, yv3 = (float)(ys).w;                     \
    float mymax = 0.0f;                                                       \
    {                                                                         \
      float sp_p, sp_m, sig;                                                  \
      bce_pieces(xv0, sp_p, sp_m, sig);                                       \
      As[0] += (posv) * yv0 * sp_m;                                           \
      Cs[0] += (posv) * (1.0f - yv0) * sp_p;                                  \
      ss[0] += yv0;                                                           \
      float om = 1.0f - sig;                                                  \
      fs += om * om * yv0 * (-sp_m);                                          \
      mymax = fmaxf(mymax, sig);                                              \
    }                                                                         \
    {                                                                         \
      float sp_p, sp_m, sig;                                                  \
      bce_pieces(xv1, sp_p, sp_m, sig);                                       \
      As[1] += (posv) * yv1 * sp_m;                                           \
      Cs[1] += (posv) * (1.0f - yv1) * sp_p;                                  \
      ss[1] += yv1;                                                           \
      float om = 1.0f - sig;                                                  \
      fs += om * om * yv1 * (-sp_m);                                          \
      mymax = fmaxf(mymax, sig);                                              \
    }                                                                         \
    {                                                                         \
      float sp_p, sp_m, sig;                                                  \
      bce_pieces(xv2, sp_p, sp_m, sig);                                       \
      As[2] += (posv) * yv2 * sp_m;                                           \
      Cs[2] += (posv) * (1.0f - yv2) * sp_p;                                  \
      ss[2] += yv2;                                                           \
      float om = 1.0f - sig;                                                  \
      fs += om * om * yv2 * (-sp_m);                                          \
      mymax = fmaxf(mymax, sig);                                              \
    }                                                                         \
    {                                                                         \
      float sp_p, sp_m, sig;                                                  \
      bce_pieces(xv3, sp_p, sp_m, sig);                                       \
      As[3] += (posv) * yv3 * sp_m;                                           \
      Cs[3] += (posv) * (1.0f - yv3) * sp_p;                                  \
      ss[3] += yv3;                                                           \
      float om = 1.0f - sig;                                                  \
      fs += om * om * yv3 * (-sp_m);                                          \
      mymax = fmaxf(mymax, sig);                                              \
    }                                                                         \
    float gmax = fmaxf(mymax, __shfl_xor(mymax, 1, 64));                      \
    if ((t & 1) == 0) {                                                       \
        hier += fmaxf(gmax - nsig, 0.0f) * (posv);                            \
        An += (posv) * nsp_m;                                                 \
        Cn += (1.0f - (posv)) * nsp_p;                                        \
        ns += (posv);                                                         \
        float om = 1.0f - nsig;                                               \
        fn += om * om * (posv) * (-nsp_m);                                    \
    }                                                                         \
  }

__global__ void __launch_bounds__(BDIM)
__attribute__((amdgpu_waves_per_eu(4, 4)))
ncl_main(
    const float* __restrict__ nlog, const float* __restrict__ slog,
    const int*   __restrict__ nlab, const int*   __restrict__ slab,
    float* __restrict__ P)
{
    __shared__ float ssc[4][3];        // per-wave scalar partials

    const int t  = threadIdx.x;
    const int g  = t >> 1;
    const int r0 = blockIdx.x * RPB;
    float* const Pb = P + (size_t)blockIdx.x * CSTRIDE;

    float As[4] = {0,0,0,0}, Cs[4] = {0,0,0,0}, ss[4] = {0,0,0,0};
    float An = 0.f, Cn = 0.f, ns = 0.f, fn = 0.f, fs = 0.f, hier = 0.f;

    const float* sp = slog + (size_t)r0 * NSUB + 4 * t;
    const int*   lp = slab + (size_t)r0 * NSUB + 4 * t;
    const float* np = nlog + (size_t)r0 * NNARR + g;
    const int*   mp = nlab + (size_t)r0 * NNARR + g;

    // 4 batches of 4 rows. 8 asm dwordx4 loads issue back-to-back
    // (hardware-pipelined, cannot be re-serialized), then drain+compute.
    #pragma unroll 1
    for (int i = 0; i < RPB; i += 4) {
        float4 xs0, xs1, xs2, xs3;
        int4   ys0, ys1, ys2, ys3;
        ASM_LOADX4F(xs0, sp + (size_t)(i + 0) * NSUB);
        ASM_LOADX4F(xs1, sp + (size_t)(i + 1) * NSUB);
        ASM_LOADX4F(xs2, sp + (size_t)(i + 2) * NSUB);
        ASM_LOADX4F(xs3, sp + (size_t)(i + 3) * NSUB);
        ASM_LOADX4I(ys0, lp + (size_t)(i + 0) * NSUB);
        ASM_LOADX4I(ys1, lp + (size_t)(i + 1) * NSUB);
        ASM_LOADX4I(ys2, lp + (size_t)(i + 2) * NSUB);
        ASM_LOADX4I(ys3, lp + (size_t)(i + 3) * NSUB);

        // scalar narrative loads (compiler-managed; drained below too)
        const float nx0 = np[(size_t)(i + 0) * NNARR];
        const float nx1 = np[(size_t)(i + 1) * NNARR];
        const float nx2 = np[(size_t)(i + 2) * NNARR];
        const float nx3 = np[(size_t)(i + 3) * NNARR];
        const float pv0 = (float)mp[(size_t)(i + 0) * NNARR];
        const float pv1 = (float)mp[(size_t)(i + 1) * NNARR];
        const float pv2 = (float)mp[(size_t)(i + 2) * NNARR];
        const float pv3 = (float)mp[(size_t)(i + 3) * NNARR];

        asm volatile("s_waitcnt vmcnt(0)" ::: "memory");
        __builtin_amdgcn_sched_barrier(0);   // nothing hoists above the drain

        ROW_BODY(xs0, ys0, nx0, pv0);
        ROW_BODY(xs1, ys1, nx1, pv1);
        ROW_BODY(xs2, ys2, nx2, pv2);
        ROW_BODY(xs3, ys3, nx3, pv3);
    }

    // exclusive per-block table: plain stores, no atomics.
    *(float4*)(Pb + WS_AS   + 4 * t) = make_float4(As[0], As[1], As[2], As[3]);
    *(float4*)(Pb + WS_CS   + 4 * t) = make_float4(Cs[0], Cs[1], Cs[2], Cs[3]);
    *(float4*)(Pb + WS_SSUM + 4 * t) = make_float4(ss[0], ss[1], ss[2], ss[3]);
    if ((t & 1) == 0) {
        Pb[WS_AN   + g] = An;
        Pb[WS_CN   + g] = Cn;
        Pb[WS_NSUM + g] = ns;
    }

    // scalar partials: wave shuffle reduce -> LDS -> thread 0
    #pragma unroll
    for (int off = 32; off; off >>= 1) {
        fn   += __shfl_down(fn,   off, 64);
        fs   += __shfl_down(fs,   off, 64);
        hier += __shfl_down(hier, off, 64);
    }
    if ((t & 63) == 0) {
        int w = t >> 6;
        ssc[w][0] = fn; ssc[w][1] = fs; ssc[w][2] = hier;
    }
    __syncthreads();
    if (t == 0) {
        float a = 0.f, b = 0.f, c = 0.f;
        #pragma unroll
        for (int w = 0; w < 4; ++w) { a += ssc[w][0]; b += ssc[w][1]; c += ssc[w][2]; }
        Pb[WS_FN] = a; Pb[WS_FS] = b; Pb[WS_HIER] = c;
    }
}

// reduce: block (e-chunk, g) sums TPG tables -> tmp[g]; fully coalesced.
__global__ __launch_bounds__(256) void ncl_reduce1(const float* __restrict__ P,
                                                   float* __restrict__ tmp)
{
    const int e = blockIdx.x * 256 + threadIdx.x;
    if (e >= WS_FLOATS) return;
    const int gg = blockIdx.y;
    const float* p = P + (size_t)gg * TPG * CSTRIDE + e;
    float s = 0.f;
    #pragma unroll 4
    for (int i = 0; i < TPG; ++i)
        s += p[(size_t)i * CSTRIDE];
    tmp[(size_t)gg * CSTRIDE + e] = s;
}

__global__ __launch_bounds__(1024) void ncl_finalize(const float* __restrict__ tmp,
                                                     float* __restrict__ out)
{
    __shared__ float sr[6][16];
    const int t = threadIdx.x;
    const float Bf = (float)NROWS;

    // sub column t, summed over the 16 chunk tables (coalesced across t)
    float As = 0.f, Csv = 0.f, ss = 0.f;
    #pragma unroll 4
    for (int gc = 0; gc < NCHUNK; ++gc) {
        const float* p = tmp + (size_t)gc * CSTRIDE;
        As  += p[WS_AS   + t];
        Csv += p[WS_CS   + t];
        ss  += p[WS_SSUM + t];
    }
    float spw = fminf(fmaxf((Bf - ss) / (ss + 1e-6f), 1.0f), 50.0f);
    float sub_part = spw * As + Csv;

    float narr_part = 0.f, valid_part = 0.f;
    if (t < NNARR) {
        float An = 0.f, Cn = 0.f, ns = 0.f;
        #pragma unroll 4
        for (int gc = 0; gc < NCHUNK; ++gc) {
            const float* p = tmp + (size_t)gc * CSTRIDE;
            An += p[WS_AN + t]; Cn += p[WS_CN + t]; ns += p[WS_NSUM + t];
        }
        float npw = fminf(fmaxf((Bf - ns) / (ns + 1e-6f), 1.0f), 50.0f);
        narr_part  = npw * An + Cn;
        valid_part = ns;
    }

    float fn_p = 0.f, fs_p = 0.f, hier_p = 0.f;
    if (t < NCHUNK) {
        const float* p = tmp + (size_t)t * CSTRIDE;
        fn_p = p[WS_FN]; fs_p = p[WS_FS]; hier_p = p[WS_HIER];
    }

    #pragma unroll
    for (int off = 32; off; off >>= 1) {
        sub_part   += __shfl_down(sub_part,   off, 64);
        narr_part  += __shfl_down(narr_part,  off, 64);
        valid_part += __shfl_down(valid_part, off, 64);
        fn_p       += __shfl_down(fn_p,       off, 64);
        fs_p       += __shfl_down(fs_p,       off, 64);
        hier_p     += __shfl_down(hier_p,     off, 64);
    }
    if ((t & 63) == 0) {
        int w = t >> 6;
        sr[0][w] = sub_part; sr[1][w] = narr_part; sr[2][w] = valid_part;
        sr[3][w] = fn_p;     sr[4][w] = fs_p;      sr[5][w] = hier_p;
    }
    __syncthreads();
    if (t == 0) {
        float sub_tot = 0.f, narr_tot = 0.f, valid = 0.f;
        float fn = 0.f, fs = 0.f, hier = 0.f;
        #pragma unroll
        for (int i = 0; i < 16; ++i) {
            sub_tot += sr[0][i]; narr_tot += sr[1][i]; valid += sr[2][i];
            fn += sr[3][i]; fs += sr[4][i]; hier += sr[5][i];
        }

        float narrative_loss = narr_tot / (Bf * (float)NNARR);
        float sub_loss = (valid > 0.0f) ? (sub_tot * (1.0f / 8.0f)) / fmaxf(valid, 1.0f) : 0.0f;
        float nf = fn / (Bf * (float)NNARR);
        float sf = fs / (Bf * (float)NSUB);
        float hier_loss = hier / Bf;

        out[0] = (narrative_loss - 0.1f * nf)
               + (sub_loss       - 0.1f * sf)
               + 0.5f * hier_loss;
    }
}

extern "C" void kernel_launch(void* const* d_in, const int* in_sizes, int n_in,
                              void* d_out, int out_size, void* d_ws, size_t ws_size,
                              hipStream_t stream) {
    const float* nlog = (const float*)d_in[0];
    const float* slog = (const float*)d_in[1];
    const int*   nlab = (const int*)d_in[2];
    const int*   slab = (const int*)d_in[3];
    float* P   = (float*)d_ws;                        // 1024 tables
    float* tmp = P + (size_t)NBLOCKS * CSTRIDE;       // 16 group tables
    float* out = (float*)d_out;

    // all workspace cells are exclusively written before read: no memset.
    ncl_main<<<NBLOCKS, BDIM, 0, stream>>>(nlog, slog, nlab, slab, P);
    dim3 gr((WS_FLOATS + 255) / 256, NCHUNK);
    ncl_reduce1<<<gr, 256, 0, stream>>>(P, tmp);
    ncl_finalize<<<1, 1024, 0, stream>>>(tmp, out);
}